// Round 3
// baseline (609.051 us; speedup 1.0000x reference)
//
#include <hip/hip_runtime.h>

// Problem constants (fixed by setup_inputs in the reference)
#define B  16
#define C  64
#define IH 256
#define IW 256
#define OH 256
#define OW 256

// Block = 16x16 output tile, ALL 64 channels sequentially (double-buffered LDS).
#define TW 16
#define TH 16
#define NWT (OW / TW)        // 16
#define NHT (OH / TH)        // 16
#define NB  (B * NHT * NWT)  // 4096 blocks (divisible by 8)
#define CAP 4096             // floats per LDS buffer (16 KB); 2 buffers = 32 KB

typedef float f4 __attribute__((ext_vector_type(4)));

__global__ __launch_bounds__(256) void ast_fused(const float* __restrict__ inp,
                                                 const float* __restrict__ theta,
                                                 float* __restrict__ out) {
    const int tid = threadIdx.x;

    // ---- vertex output folded into hardware block 0 (tiny: 128 floats) ----
    if (blockIdx.x == 0 && tid < B * 4) {
        const int b_ = tid >> 2;
        const int v  = tid & 3;
        const float vx_tab[4] = {-1.0f, -1.0f, 1.0f, 1.0f};
        const float vy_tab[4] = {-1.0f,  1.0f, 1.0f, -1.0f};
        const float Vx = vx_tab[v];
        const float Vy = vy_tab[v];
        const float ox = theta[b_*6+0]*Vx + theta[b_*6+1]*Vy + theta[b_*6+2];
        const float oy = theta[b_*6+3]*Vx + theta[b_*6+4]*Vy + theta[b_*6+5];
        float* vo = out + (size_t)B * C * OH * OW;
        vo[b_*8 + v*2 + 0] = (ox + 1.0f) * ((float)IW * 0.5f);
        vo[b_*8 + v*2 + 1] = (oy + 1.0f) * ((float)IH * 0.5f);
    }

    // ---- XCD-chunked bijective swizzle: each XCD owns 512 contiguous ids
    // (= 2 complete batches) -> input rows shared between neighbor tiles
    // stay in that XCD's L2. 4096 % 8 == 0 -> bijective. ----
    int id = (int)blockIdx.x;
    id = (id & 7) * (NB >> 3) + (id >> 3);

    const int wt = id & (NWT - 1);
    const int ht = (id >> 4) & (NHT - 1);
    const int b  = id >> 8;

    const int tx = tid & (TW - 1);
    const int ty = tid >> 4;
    const int w = wt * TW + tx;
    const int h = ht * TH + ty;

    const float t00 = theta[b*6+0], t01 = theta[b*6+1], t02 = theta[b*6+2];
    const float t10 = theta[b*6+3], t11 = theta[b*6+4], t12 = theta[b*6+5];

    const float sWn = 2.0f / (float)(OW - 1);
    const float sHn = 2.0f / (float)(OH - 1);

    // per-thread sample coordinates (align_corners linspace)
    const float wn = -1.0f + sWn * (float)w;
    const float hn = -1.0f + sHn * (float)h;
    const float ix = (t00 * wn + t01 * hn + t02 + 1.0f) * ((float)(IW - 1) * 0.5f);
    const float iy = (t10 * wn + t11 * hn + t12 + 1.0f) * ((float)(IH - 1) * 0.5f);

    const float x0f = floorf(ix);
    const float y0f = floorf(iy);
    const float wx1 = ix - x0f;
    const float wy1 = iy - y0f;
    const float wx0 = 1.0f - wx1;
    const float wy0 = 1.0f - wy1;

    const bool inx0 = (x0f >= 0.0f) && (x0f <= (float)(IW - 1));
    const bool inx1 = (x0f + 1.0f >= 0.0f) && (x0f + 1.0f <= (float)(IW - 1));
    const bool iny0 = (y0f >= 0.0f) && (y0f <= (float)(IH - 1));
    const bool iny1 = (y0f + 1.0f >= 0.0f) && (y0f + 1.0f <= (float)(IH - 1));

    const float w00 = (inx0 && iny0) ? wx0 * wy0 : 0.0f;
    const float w10 = (inx1 && iny0) ? wx1 * wy0 : 0.0f;
    const float w01 = (inx0 && iny1) ? wx0 * wy1 : 0.0f;
    const float w11 = (inx1 && iny1) ? wx1 * wy1 : 0.0f;

    // ---- tile bbox from the 4 tile corners (affine => extremes at corners) ----
    const float wnA = -1.0f + sWn * (float)(wt * TW);
    const float wnB = -1.0f + sWn * (float)(wt * TW + TW - 1);
    const float hnA = -1.0f + sHn * (float)(ht * TH);
    const float hnB = -1.0f + sHn * (float)(ht * TH + TH - 1);

    const float ixAA = (t00*wnA + t01*hnA + t02 + 1.0f) * 127.5f;
    const float ixAB = (t00*wnA + t01*hnB + t02 + 1.0f) * 127.5f;
    const float ixBA = (t00*wnB + t01*hnA + t02 + 1.0f) * 127.5f;
    const float ixBB = (t00*wnB + t01*hnB + t02 + 1.0f) * 127.5f;
    const float iyAA = (t10*wnA + t11*hnA + t12 + 1.0f) * 127.5f;
    const float iyAB = (t10*wnA + t11*hnB + t12 + 1.0f) * 127.5f;
    const float iyBA = (t10*wnB + t11*hnA + t12 + 1.0f) * 127.5f;
    const float iyBB = (t10*wnB + t11*hnB + t12 + 1.0f) * 127.5f;

    const float min_ix = fminf(fminf(ixAA, ixAB), fminf(ixBA, ixBB));
    const float max_ix = fmaxf(fmaxf(ixAA, ixAB), fmaxf(ixBA, ixBB));
    const float min_iy = fminf(fminf(iyAA, iyAB), fminf(iyBA, iyBB));
    const float max_iy = fmaxf(fmaxf(iyAA, iyAB), fmaxf(iyBA, iyBB));

    float* o = out + ((size_t)(b * C) << 16) + (size_t)(h * OW + w);

    // ---- whole-tile-OOB fast path: pure zero stores, no barriers ----
    if (max_ix < -1.0f || min_ix > 256.0f || max_iy < -1.0f || min_iy > 256.0f) {
        #pragma unroll 8
        for (int c = 0; c < C; ++c) {
            __builtin_nontemporal_store(0.0f, o);
            o += OH * OW;
        }
        return;
    }

    // ---- integer bbox, pow2 pitch ----
    int bx0 = min(max((int)floorf(min_ix), 0), IW - 1);
    int bx1 = min(min(max((int)floorf(max_ix), 0), IW - 1) + 1, IW - 1);
    int by0 = min(max((int)floorf(min_iy), 0), IH - 1);
    int by1 = min(min(max((int)floorf(max_iy), 0), IH - 1) + 1, IH - 1);
    const int Wd = bx1 - bx0 + 1;
    const int Hd = by1 - by0 + 1;
    const int lw  = 32 - __builtin_clz((unsigned)max(Wd - 1, 3)); // Wp = pow2ceil(Wd), min 4
    const int Wp  = 1 << lw;
    const int msk = Wp - 1;
    const int bx0p = min(bx0, IW - Wp);   // shift window left so full Wp width is in-image
    const int HWp = Hd << lw;

    // clamped per-thread corner indices (weights are 0 wherever clamping matters)
    const int x0i = (int)x0f;
    const int y0i = (int)y0f;
    const int x0c = min(max(x0i,     bx0), bx1);
    const int x1c = min(max(x0i + 1, bx0), bx1);
    const int y0c = min(max(y0i,     by0), by1);
    const int y1c = min(max(y0i + 1, by0), by1);

    const float* plane0 = inp + ((size_t)(b * C) << 16);

    if (HWp > CAP) {
        // ---- rare fallback (huge bbox): per-thread global gathers ----
        const int a00 = y0c * IW + x0c;
        const int a01 = y0c * IW + x1c;
        const int a10 = y1c * IW + x0c;
        const int a11 = y1c * IW + x1c;
        const float* pl = plane0;
        for (int c = 0; c < C; ++c) {
            float v = w00 * pl[a00];
            v = fmaf(w10, pl[a01], v);
            v = fmaf(w01, pl[a10], v);
            v = fmaf(w11, pl[a11], v);
            __builtin_nontemporal_store(v, o);
            pl += IH * IW;
            o  += OH * OW;
        }
        return;
    }

    // ---- per-thread LDS sample offsets (channel-invariant), XOR-swizzled ----
    const int xr0 = x0c - bx0p;
    const int xr1 = x1c - bx0p;
    const int r0  = y0c - by0;
    const int r1  = y1c - by0;
    const int o00 = (r0 << lw) + (xr0 ^ (r0 & msk));
    const int o01 = (r0 << lw) + (xr1 ^ (r0 & msk));
    const int o10 = (r1 << lw) + (xr0 ^ (r1 & msk));
    const int o11 = (r1 << lw) + (xr1 ^ (r1 & msk));

    // ---- staging metadata: dest-linear groups of 4 floats, XOR-unswizzled src ----
    int  ga[4][4];
    bool act[4];
    #pragma unroll
    for (int g = 0; g < 4; ++g) {
        const int i4 = g * 1024 + (tid << 2);
        act[g] = (i4 < HWp);
        const int r  = i4 >> lw;
        const int xb = i4 & msk;
        const int rowo = (by0 + r) * IW + bx0p;
        const int rx = r & msk;
        #pragma unroll
        for (int j = 0; j < 4; ++j)
            ga[g][j] = rowo + ((xb + j) ^ rx);
    }

    __shared__ float sb[2][CAP];

    // prefetch channel 0 into registers
    f4 pf[4];
    #pragma unroll
    for (int g = 0; g < 4; ++g) {
        if (act[g]) {
            pf[g].x = plane0[ga[g][0]];
            pf[g].y = plane0[ga[g][1]];
            pf[g].z = plane0[ga[g][2]];
            pf[g].w = plane0[ga[g][3]];
        }
    }

    #pragma unroll 2
    for (int c = 0; c < C; ++c) {
        const int cur = c & 1;
        // write staged registers of channel c into current buffer
        float* dst = &sb[cur][0];
        #pragma unroll
        for (int g = 0; g < 4; ++g) {
            if (act[g]) *(f4*)&dst[g * 1024 + (tid << 2)] = pf[g];
        }
        // issue next channel's loads (latency hides under sampling below)
        if (c + 1 < C) {
            const float* pl = plane0 + ((size_t)(c + 1) << 16);
            #pragma unroll
            for (int g = 0; g < 4; ++g) {
                if (act[g]) {
                    pf[g].x = pl[ga[g][0]];
                    pf[g].y = pl[ga[g][1]];
                    pf[g].z = pl[ga[g][2]];
                    pf[g].w = pl[ga[g][3]];
                }
            }
        }
        __syncthreads();
        // sample from LDS
        const float* Lb = &sb[cur][0];
        float v = w00 * Lb[o00];
        v = fmaf(w10, Lb[o01], v);
        v = fmaf(w01, Lb[o10], v);
        v = fmaf(w11, Lb[o11], v);
        __builtin_nontemporal_store(v, o);
        o += OH * OW;
    }
}

extern "C" void kernel_launch(void* const* d_in, const int* in_sizes, int n_in,
                              void* d_out, int out_size, void* d_ws, size_t ws_size,
                              hipStream_t stream) {
    const float* inp   = (const float*)d_in[0];
    const float* theta = (const float*)d_in[1];
    float* out = (float*)d_out;

    ast_fused<<<NB, 256, 0, stream>>>(inp, theta, out);
}

// Round 4
// 579.948 us; speedup vs baseline: 1.0502x; 1.0502x over previous
//
#include <hip/hip_runtime.h>

// Problem constants (fixed by setup_inputs in the reference)
#define B  16
#define C  64
#define IH 256
#define IW 256
#define OH 256
#define OW 256

// Block = 16x16 output tile, ALL 64 channels sequentially, double-buffered LDS.
#define TW 16
#define TH 16
#define NWT (OW / TW)        // 16
#define NHT (OH / TH)        // 16
#define NB  (B * NHT * NWT)  // 4096 blocks (divisible by 8)
#define CAP 4096             // floats per LDS buffer (16 KB); 2 buffers = 32 KB

typedef float f4 __attribute__((ext_vector_type(4)));
typedef float f2 __attribute__((ext_vector_type(2)));
typedef f2 __attribute__((aligned(4))) f2u;

__global__ __launch_bounds__(256) void ast_fused(const float* __restrict__ inp,
                                                 const float* __restrict__ theta,
                                                 float* __restrict__ out) {
    const int tid = threadIdx.x;

    // ---- vertex output folded into hardware block 0 (tiny: 128 floats) ----
    if (blockIdx.x == 0 && tid < B * 4) {
        const int b_ = tid >> 2;
        const int v  = tid & 3;
        const float vx_tab[4] = {-1.0f, -1.0f, 1.0f, 1.0f};
        const float vy_tab[4] = {-1.0f,  1.0f, 1.0f, -1.0f};
        const float Vx = vx_tab[v];
        const float Vy = vy_tab[v];
        const float ox = theta[b_*6+0]*Vx + theta[b_*6+1]*Vy + theta[b_*6+2];
        const float oy = theta[b_*6+3]*Vx + theta[b_*6+4]*Vy + theta[b_*6+5];
        float* vo = out + (size_t)B * C * OH * OW;
        vo[b_*8 + v*2 + 0] = (ox + 1.0f) * ((float)IW * 0.5f);
        vo[b_*8 + v*2 + 1] = (oy + 1.0f) * ((float)IH * 0.5f);
    }

    // ---- XCD-chunked bijective swizzle (512 contiguous ids = 2 batches/XCD) ----
    int id = (int)blockIdx.x;
    id = (id & 7) * (NB >> 3) + (id >> 3);

    const int wt = id & (NWT - 1);
    const int ht = (id >> 4) & (NHT - 1);
    const int b  = id >> 8;

    const int tx = tid & (TW - 1);
    const int ty = tid >> 4;
    const int w = wt * TW + tx;
    const int h = ht * TH + ty;

    const float t00 = theta[b*6+0], t01 = theta[b*6+1], t02 = theta[b*6+2];
    const float t10 = theta[b*6+3], t11 = theta[b*6+4], t12 = theta[b*6+5];

    const float sWn = 2.0f / (float)(OW - 1);
    const float sHn = 2.0f / (float)(OH - 1);

    // per-thread sample coordinates (align_corners linspace)
    const float wn = -1.0f + sWn * (float)w;
    const float hn = -1.0f + sHn * (float)h;
    const float ix = (t00 * wn + t01 * hn + t02 + 1.0f) * ((float)(IW - 1) * 0.5f);
    const float iy = (t10 * wn + t11 * hn + t12 + 1.0f) * ((float)(IH - 1) * 0.5f);

    const float x0f = floorf(ix);
    const float y0f = floorf(iy);
    const float wx1 = ix - x0f;
    const float wy1 = iy - y0f;
    const float wx0 = 1.0f - wx1;
    const float wy0 = 1.0f - wy1;

    const bool inx0 = (x0f >= 0.0f) && (x0f <= (float)(IW - 1));
    const bool inx1 = (x0f + 1.0f >= 0.0f) && (x0f + 1.0f <= (float)(IW - 1));
    const bool iny0 = (y0f >= 0.0f) && (y0f <= (float)(IH - 1));
    const bool iny1 = (y0f + 1.0f >= 0.0f) && (y0f + 1.0f <= (float)(IH - 1));

    const float w00 = (inx0 && iny0) ? wx0 * wy0 : 0.0f;
    const float w10 = (inx1 && iny0) ? wx1 * wy0 : 0.0f;
    const float w01 = (inx0 && iny1) ? wx0 * wy1 : 0.0f;
    const float w11 = (inx1 && iny1) ? wx1 * wy1 : 0.0f;

    // ---- tile bbox from the 4 tile corners (affine => extremes at corners) ----
    const float wnA = -1.0f + sWn * (float)(wt * TW);
    const float wnB = -1.0f + sWn * (float)(wt * TW + TW - 1);
    const float hnA = -1.0f + sHn * (float)(ht * TH);
    const float hnB = -1.0f + sHn * (float)(ht * TH + TH - 1);

    const float ixAA = (t00*wnA + t01*hnA + t02 + 1.0f) * 127.5f;
    const float ixAB = (t00*wnA + t01*hnB + t02 + 1.0f) * 127.5f;
    const float ixBA = (t00*wnB + t01*hnA + t02 + 1.0f) * 127.5f;
    const float ixBB = (t00*wnB + t01*hnB + t02 + 1.0f) * 127.5f;
    const float iyAA = (t10*wnA + t11*hnA + t12 + 1.0f) * 127.5f;
    const float iyAB = (t10*wnA + t11*hnB + t12 + 1.0f) * 127.5f;
    const float iyBA = (t10*wnB + t11*hnA + t12 + 1.0f) * 127.5f;
    const float iyBB = (t10*wnB + t11*hnB + t12 + 1.0f) * 127.5f;

    const float min_ix = fminf(fminf(ixAA, ixAB), fminf(ixBA, ixBB));
    const float max_ix = fmaxf(fmaxf(ixAA, ixAB), fmaxf(ixBA, ixBB));
    const float min_iy = fminf(fminf(iyAA, iyAB), fminf(iyBA, iyBB));
    const float max_iy = fmaxf(fmaxf(iyAA, iyAB), fmaxf(iyBA, iyBB));

    float* o = out + ((size_t)(b * C) << 16) + (size_t)(h * OW + w);

    // ---- whole-tile-OOB fast path: pure zero stores, no barriers ----
    if (max_ix < -1.0f || min_ix > 256.0f || max_iy < -1.0f || min_iy > 256.0f) {
        #pragma unroll 8
        for (int c = 0; c < C; ++c) {
            __builtin_nontemporal_store(0.0f, o);
            o += OH * OW;
        }
        return;
    }

    // ---- integer bbox (+-1 safety expansion; weights are 0 wherever clamps bite) ----
    const int bx0 = min(max((int)floorf(min_ix) - 1, 0), IW - 1);
    const int bx1 = min(max((int)floorf(max_ix) + 2, 0), IW - 1);
    const int by0 = min(max((int)floorf(min_iy) - 1, 0), IH - 1);
    const int by1 = min(max((int)floorf(max_iy) + 2, 0), IH - 1);

    const int Wneed = bx1 - bx0 + 4;                      // width + pair margin
    int lw = 32 - __builtin_clz((unsigned)(Wneed - 1));   // pow2ceil
    if (lw < 3) lw = 3;
    if (lw > 8) lw = 8;
    const int P   = 1 << lw;                              // staged row width (pow2)
    const int Pp  = P + 4;                                // LDS pitch: P'%8==4 -> rows shift 4 banks
    const int ax0p = min(bx0 & ~3, IW - P);               // 16B-aligned window start, in-image
    const int Hd  = by1 - by0 + 1;

    const int x0i = (int)x0f;
    const int y0i = (int)y0f;
    const float* plane = inp + ((size_t)(b * C) << 16);

    if (Hd * Pp > CAP) {
        // ---- rare fallback (huge bbox): R0-style paired direct gathers ----
        const int  basex = min(max(x0i, 0), IW - 2);
        const bool sA = (x0i <= IW - 2);
        const bool sB = (x0i >= 0);
        const int  y0c = min(max(y0i,     0), IH - 1);
        const int  y1c = min(max(y0i + 1, 0), IH - 1);
        const int off0 = y0c * IW + basex;
        const int off1 = y1c * IW + basex;
        const float* pl = plane;
        for (int c = 0; c < C; ++c) {
            const f2 ra = *(const f2u*)(pl + off0);
            const f2 rb = *(const f2u*)(pl + off1);
            const float a00 = sA ? ra.x : ra.y;
            const float a10 = sB ? ra.y : ra.x;
            const float b00 = sA ? rb.x : rb.y;
            const float b11 = sB ? rb.y : rb.x;
            float v = w00 * a00;
            v = fmaf(w10, a10, v);
            v = fmaf(w01, b00, v);
            v = fmaf(w11, b11, v);
            __builtin_nontemporal_store(v, o);
            pl += IH * IW;
            o  += OH * OW;
        }
        return;
    }

    // ---- per-thread sample offsets into the LDS window (channel-invariant) ----
    const int xin = x0i - ax0p;
    const int rin = y0i - by0;
    const int xc0 = min(max(xin, 0), P - 2);
    const bool selA = (xin <= P - 2);     // x0 corner = pair.x unless clamped right
    const bool selB = (xin >= 0);         // x1 corner = pair.y unless clamped left
    const int r0 = min(max(rin,     0), Hd - 1);
    const int r1 = min(max(rin + 1, 0), Hd - 1);
    const int ad0 = r0 * Pp + xc0;
    const int ad1 = r1 * Pp + xc0;

    // ---- staging map: LINEAR lane->window (coalesced dwordx4 global loads) ----
    const int S = Hd << lw;               // staged floats (P-wide rows)
    int  gsrc[4];
    int  ldst[4];
    bool act[4];
    #pragma unroll
    for (int g = 0; g < 4; ++g) {
        const int i4 = g * 1024 + (tid << 2);
        act[g] = (i4 < S);
        const int r  = i4 >> lw;
        const int xb = i4 & (P - 1);
        gsrc[g] = (by0 + r) * IW + ax0p + xb;   // consecutive lanes -> consecutive 16B
        ldst[g] = r * Pp + xb;                  // linear row, padded pitch
    }

    __shared__ float sb[2][CAP];

    // prefetch channel 0 into registers (T14: issue early, write late)
    f4 pf[4];
    #pragma unroll
    for (int g = 0; g < 4; ++g)
        if (act[g]) pf[g] = *(const f4*)(plane + gsrc[g]);

    #pragma unroll 2
    for (int c = 0; c < C; ++c) {
        const int cur = c & 1;
        float* dst = &sb[cur][0];
        #pragma unroll
        for (int g = 0; g < 4; ++g)
            if (act[g]) *(f4*)(dst + ldst[g]) = pf[g];
        // issue next channel's coalesced loads; latency hides under sampling below
        if (c + 1 < C) {
            const float* pl = plane + ((size_t)(c + 1) << 16);
            #pragma unroll
            for (int g = 0; g < 4; ++g)
                if (act[g]) pf[g] = *(const f4*)(pl + gsrc[g]);
        }
        __syncthreads();
        // sample from LDS: two adjacent-dword pairs -> ds_read2_b32
        const float* Lb = &sb[cur][0];
        const float p00 = Lb[ad0], p01 = Lb[ad0 + 1];
        const float p10 = Lb[ad1], p11 = Lb[ad1 + 1];
        const float a00 = selA ? p00 : p01;
        const float a10 = selB ? p01 : p00;
        const float b00 = selA ? p10 : p11;
        const float b11 = selB ? p11 : p10;
        float v = w00 * a00;
        v = fmaf(w10, a10, v);
        v = fmaf(w01, b00, v);
        v = fmaf(w11, b11, v);
        __builtin_nontemporal_store(v, o);
        o += OH * OW;
    }
}

extern "C" void kernel_launch(void* const* d_in, const int* in_sizes, int n_in,
                              void* d_out, int out_size, void* d_ws, size_t ws_size,
                              hipStream_t stream) {
    const float* inp   = (const float*)d_in[0];
    const float* theta = (const float*)d_in[1];
    float* out = (float*)d_out;

    ast_fused<<<NB, 256, 0, stream>>>(inp, theta, out);
}

// Round 5
// 529.483 us; speedup vs baseline: 1.1503x; 1.0953x over previous
//
#include <hip/hip_runtime.h>

// Problem constants (fixed by setup_inputs in the reference)
#define B  16
#define C  64
#define IH 256
#define IW 256
#define OH 256
#define OW 256

// Block = 16x16 output tile, ALL 64 channels, depth-2 software pipeline.
#define TW 16
#define TH 16
#define NWT (OW / TW)        // 16
#define NHT (OH / TH)        // 16
#define NB  (B * NHT * NWT)  // 4096 blocks (divisible by 8)
#define CAPU 2048            // usable floats per LDS buffer
#define CAPF (CAPU + 256)    // + dump strip (inactive-lane writes land here)

typedef float f4 __attribute__((ext_vector_type(4)));
typedef float f2 __attribute__((ext_vector_type(2)));
typedef f2 __attribute__((aligned(4))) f2u;

// LDS-visibility barrier WITHOUT __syncthreads' vmcnt(0) drain:
// prefetched global loads stay in flight across it (T3/T4 counted-wait).
#define BAR() do {                                         \
    asm volatile("s_waitcnt lgkmcnt(0)" ::: "memory");     \
    __builtin_amdgcn_s_barrier();                          \
    asm volatile("" ::: "memory");                         \
} while (0)

__global__ __launch_bounds__(256, 8) void ast_fused(const float* __restrict__ inp,
                                                    const float* __restrict__ theta,
                                                    float* __restrict__ out) {
    const int tid = threadIdx.x;

    // ---- vertex output folded into hardware block 0 (tiny: 128 floats) ----
    if (blockIdx.x == 0 && tid < B * 4) {
        const int b_ = tid >> 2;
        const int v  = tid & 3;
        const float vx_tab[4] = {-1.0f, -1.0f, 1.0f, 1.0f};
        const float vy_tab[4] = {-1.0f,  1.0f, 1.0f, -1.0f};
        const float Vx = vx_tab[v];
        const float Vy = vy_tab[v];
        const float ox = theta[b_*6+0]*Vx + theta[b_*6+1]*Vy + theta[b_*6+2];
        const float oy = theta[b_*6+3]*Vx + theta[b_*6+4]*Vy + theta[b_*6+5];
        float* vo = out + (size_t)B * C * OH * OW;
        vo[b_*8 + v*2 + 0] = (ox + 1.0f) * ((float)IW * 0.5f);
        vo[b_*8 + v*2 + 1] = (oy + 1.0f) * ((float)IH * 0.5f);
    }

    // ---- XCD-chunked bijective swizzle (512 contiguous ids = 2 batches/XCD) ----
    int id = (int)blockIdx.x;
    id = (id & 7) * (NB >> 3) + (id >> 3);

    const int wt = id & (NWT - 1);
    const int ht = (id >> 4) & (NHT - 1);
    const int b  = id >> 8;

    const int tx = tid & (TW - 1);
    const int ty = tid >> 4;
    const int w = wt * TW + tx;
    const int h = ht * TH + ty;

    const float t00 = theta[b*6+0], t01 = theta[b*6+1], t02 = theta[b*6+2];
    const float t10 = theta[b*6+3], t11 = theta[b*6+4], t12 = theta[b*6+5];

    const float sWn = 2.0f / (float)(OW - 1);
    const float sHn = 2.0f / (float)(OH - 1);

    // per-thread sample coordinates (align_corners linspace)
    const float wn = -1.0f + sWn * (float)w;
    const float hn = -1.0f + sHn * (float)h;
    const float ix = (t00 * wn + t01 * hn + t02 + 1.0f) * ((float)(IW - 1) * 0.5f);
    const float iy = (t10 * wn + t11 * hn + t12 + 1.0f) * ((float)(IH - 1) * 0.5f);

    const float x0f = floorf(ix);
    const float y0f = floorf(iy);
    const float wx1 = ix - x0f;
    const float wy1 = iy - y0f;
    const float wx0 = 1.0f - wx1;
    const float wy0 = 1.0f - wy1;

    const bool inx0 = (x0f >= 0.0f) && (x0f <= (float)(IW - 1));
    const bool inx1 = (x0f + 1.0f >= 0.0f) && (x0f + 1.0f <= (float)(IW - 1));
    const bool iny0 = (y0f >= 0.0f) && (y0f <= (float)(IH - 1));
    const bool iny1 = (y0f + 1.0f >= 0.0f) && (y0f + 1.0f <= (float)(IH - 1));

    const float w00 = (inx0 && iny0) ? wx0 * wy0 : 0.0f;
    const float w10 = (inx1 && iny0) ? wx1 * wy0 : 0.0f;
    const float w01 = (inx0 && iny1) ? wx0 * wy1 : 0.0f;
    const float w11 = (inx1 && iny1) ? wx1 * wy1 : 0.0f;

    // ---- tile bbox from the 4 tile corners (affine => extremes at corners) ----
    const float wnA = -1.0f + sWn * (float)(wt * TW);
    const float wnB = -1.0f + sWn * (float)(wt * TW + TW - 1);
    const float hnA = -1.0f + sHn * (float)(ht * TH);
    const float hnB = -1.0f + sHn * (float)(ht * TH + TH - 1);

    const float ixAA = (t00*wnA + t01*hnA + t02 + 1.0f) * 127.5f;
    const float ixAB = (t00*wnA + t01*hnB + t02 + 1.0f) * 127.5f;
    const float ixBA = (t00*wnB + t01*hnA + t02 + 1.0f) * 127.5f;
    const float ixBB = (t00*wnB + t01*hnB + t02 + 1.0f) * 127.5f;
    const float iyAA = (t10*wnA + t11*hnA + t12 + 1.0f) * 127.5f;
    const float iyAB = (t10*wnA + t11*hnB + t12 + 1.0f) * 127.5f;
    const float iyBA = (t10*wnB + t11*hnA + t12 + 1.0f) * 127.5f;
    const float iyBB = (t10*wnB + t11*hnB + t12 + 1.0f) * 127.5f;

    const float min_ix = fminf(fminf(ixAA, ixAB), fminf(ixBA, ixBB));
    const float max_ix = fmaxf(fmaxf(ixAA, ixAB), fmaxf(ixBA, ixBB));
    const float min_iy = fminf(fminf(iyAA, iyAB), fminf(iyBA, iyBB));
    const float max_iy = fmaxf(fmaxf(iyAA, iyAB), fmaxf(iyBA, iyBB));

    float* o = out + ((size_t)(b * C) << 16) + (size_t)(h * OW + w);

    // ---- whole-tile-OOB fast path: pure zero stores, no barriers ----
    if (max_ix < -1.0f || min_ix > 256.0f || max_iy < -1.0f || min_iy > 256.0f) {
        #pragma unroll 8
        for (int c = 0; c < C; ++c) {
            __builtin_nontemporal_store(0.0f, o);
            o += OH * OW;
        }
        return;
    }

    // ---- integer bbox (+-1 safety; weights are 0 wherever clamps bite) ----
    const int bx0 = min(max((int)floorf(min_ix) - 1, 0), IW - 1);
    const int bx1 = min(max((int)floorf(max_ix) + 2, 0), IW - 1);
    const int by0 = min(max((int)floorf(min_iy) - 1, 0), IH - 1);
    const int by1 = min(max((int)floorf(max_iy) + 2, 0), IH - 1);

    const int Wneed = bx1 - bx0 + 4;
    int lw = 32 - __builtin_clz((unsigned)(Wneed - 1));   // pow2ceil
    if (lw < 3) lw = 3;
    if (lw > 8) lw = 8;
    const int P    = 1 << lw;
    const int Pp   = P + 4;                  // pitch: rows shift 4 banks
    const int ax0p = min(bx0 & ~3, IW - P);  // 16B-aligned window start
    const int Hd   = by1 - by0 + 1;

    const int x0i = (int)x0f;
    const int y0i = (int)y0f;
    const float* plane = inp + ((size_t)(b * C) << 16);

    if (Hd * Pp > CAPU) {
        // ---- rare fallback (huge bbox): R0-style paired direct gathers ----
        const int  basex = min(max(x0i, 0), IW - 2);
        const bool sA = (x0i <= IW - 2);
        const bool sB = (x0i >= 0);
        const int  y0c = min(max(y0i,     0), IH - 1);
        const int  y1c = min(max(y0i + 1, 0), IH - 1);
        const int off0 = y0c * IW + basex;
        const int off1 = y1c * IW + basex;
        const float* pl = plane;
        for (int c = 0; c < C; ++c) {
            const f2 ra = *(const f2u*)(pl + off0);
            const f2 rb = *(const f2u*)(pl + off1);
            const float a00 = sA ? ra.x : ra.y;
            const float a10 = sB ? ra.y : ra.x;
            const float b00 = sA ? rb.x : rb.y;
            const float b11 = sB ? rb.y : rb.x;
            float v = w00 * a00;
            v = fmaf(w10, a10, v);
            v = fmaf(w01, b00, v);
            v = fmaf(w11, b11, v);
            __builtin_nontemporal_store(v, o);
            pl += IH * IW;
            o  += OH * OW;
        }
        return;
    }

    // ---- per-thread LDS sample offsets (channel-invariant) ----
    const int xin = x0i - ax0p;
    const int rin = y0i - by0;
    const int xc0 = min(max(xin, 0), P - 2);
    const bool selA = (xin <= P - 2);
    const bool selB = (xin >= 0);
    const int r0 = min(max(rin,     0), Hd - 1);
    const int r1 = min(max(rin + 1, 0), Hd - 1);
    const int ad0 = r0 * Pp + xc0;
    const int ad1 = r1 * Pp + xc0;

    // ---- staging map: LINEAR lane->window; UNCONDITIONAL 2 groups so the
    // per-wave outstanding-load count is uniform (counted vmcnt, no drain) ----
    const int S = Hd << lw;
    int gsrc[2], ldst[2];
    #pragma unroll
    for (int g = 0; g < 2; ++g) {
        const int i4 = g * 1024 + (tid << 2);
        if (i4 < S) {
            const int r  = i4 >> lw;
            const int xb = i4 & (P - 1);
            gsrc[g] = (by0 + r) * IW + ax0p + xb;   // coalesced dwordx4
            ldst[g] = r * Pp + xb;
        } else {
            gsrc[g] = by0 * IW + ax0p;              // L1-hot dummy (valid addr)
            ldst[g] = CAPU + ((tid & 63) << 2);     // dump strip, conflict-free
        }
    }

    __shared__ float sb[2][CAPF];
    float* const b0 = &sb[0][0];
    float* const b1 = &sb[1][0];

    auto samp = [&](const float* Lb) -> float {
        const float p00 = Lb[ad0], p01 = Lb[ad0 + 1];
        const float p10 = Lb[ad1], p11 = Lb[ad1 + 1];
        const float a00 = selA ? p00 : p01;
        const float a10 = selB ? p01 : p00;
        const float c00 = selA ? p10 : p11;
        const float c11 = selB ? p11 : p10;
        float v = w00 * a00;
        v = fmaf(w10, a10, v);
        v = fmaf(w01, c00, v);
        v = fmaf(w11, c11, v);
        return v;
    };

    // ---- depth-2 pipelined channel loop: 1 raw barrier per channel,
    // loads issued a FULL phase before their ds_write (latency hidden) ----
    const float* pld = plane;
    f4 pfA0, pfA1, pfB0, pfB1;

    // prologue: ch0 -> buf0 (one-time exposed latency), ch1 in flight
    pfA0 = *(const f4*)(pld + gsrc[0]);
    pfA1 = *(const f4*)(pld + gsrc[1]);
    pld += IH * IW;
    pfB0 = *(const f4*)(pld + gsrc[0]);
    pfB1 = *(const f4*)(pld + gsrc[1]);
    pld += IH * IW;
    *(f4*)(b0 + ldst[0]) = pfA0;       // compiler: counted vmcnt (pfB in flight)
    *(f4*)(b0 + ldst[1]) = pfA1;
    BAR();

    #pragma unroll 1
    for (int k = 0; k < 31; ++k) {
        // even phase: sample ch 2k from buf0; write ch 2k+1; issue ch 2k+2
        pfA0 = *(const f4*)(pld + gsrc[0]);
        pfA1 = *(const f4*)(pld + gsrc[1]);
        pld += IH * IW;
        *(f4*)(b1 + ldst[0]) = pfB0;   // vmcnt(2): waits pfB only, pfA flies on
        *(f4*)(b1 + ldst[1]) = pfB1;
        const float v0 = samp(b0);
        BAR();
        __builtin_nontemporal_store(v0, o);
        o += OH * OW;

        // odd phase: sample ch 2k+1 from buf1; write ch 2k+2; issue ch 2k+3
        pfB0 = *(const f4*)(pld + gsrc[0]);
        pfB1 = *(const f4*)(pld + gsrc[1]);
        pld += IH * IW;
        *(f4*)(b0 + ldst[0]) = pfA0;
        *(f4*)(b0 + ldst[1]) = pfA1;
        const float v1 = samp(b1);
        BAR();
        __builtin_nontemporal_store(v1, o);
        o += OH * OW;
    }

    // epilogue: ch62 in buf0; ch63 in pfB
    *(f4*)(b1 + ldst[0]) = pfB0;
    *(f4*)(b1 + ldst[1]) = pfB1;
    const float v62 = samp(b0);
    BAR();
    __builtin_nontemporal_store(v62, o);
    o += OH * OW;
    const float v63 = samp(b1);
    __builtin_nontemporal_store(v63, o);
}

extern "C" void kernel_launch(void* const* d_in, const int* in_sizes, int n_in,
                              void* d_out, int out_size, void* d_ws, size_t ws_size,
                              hipStream_t stream) {
    const float* inp   = (const float*)d_in[0];
    const float* theta = (const float*)d_in[1];
    float* out = (float*)d_out;

    ast_fused<<<NB, 256, 0, stream>>>(inp, theta, out);
}

// Round 6
// 527.789 us; speedup vs baseline: 1.1540x; 1.0032x over previous
//
#include <hip/hip_runtime.h>

// Problem constants (fixed by setup_inputs in the reference)
#define B  16
#define C  64
#define IH 256
#define IW 256
#define OH 256
#define OW 256

// Block = 16x16 output tile, 64 channels in 32 PAIRS, depth-2-pair pipeline.
#define TW 16
#define TH 16
#define NWT (OW / TW)        // 16
#define NHT (OH / TH)        // 16
#define NB  (B * NHT * NWT)  // 4096 blocks (divisible by 8)
#define CAPU 1280            // usable floats per channel slot
#define CAPF 1536            // + dump strip; 4 slots = 24 KB -> 6 blocks/CU

typedef float f4 __attribute__((ext_vector_type(4)));
typedef float f2 __attribute__((ext_vector_type(2)));
typedef f2 __attribute__((aligned(4))) f2u;

// LDS-visibility barrier WITHOUT __syncthreads' vmcnt(0) drain:
// prefetched global loads stay in flight across it (T3/T4 counted-wait).
#define BAR() do {                                         \
    asm volatile("s_waitcnt lgkmcnt(0)" ::: "memory");     \
    __builtin_amdgcn_s_barrier();                          \
    asm volatile("" ::: "memory");                         \
} while (0)

__global__ __launch_bounds__(256, 6) void ast_fused(const float* __restrict__ inp,
                                                    const float* __restrict__ theta,
                                                    float* __restrict__ out) {
    const int tid = threadIdx.x;

    // ---- vertex output folded into hardware block 0 (tiny: 128 floats) ----
    if (blockIdx.x == 0 && tid < B * 4) {
        const int b_ = tid >> 2;
        const int v  = tid & 3;
        const float vx_tab[4] = {-1.0f, -1.0f, 1.0f, 1.0f};
        const float vy_tab[4] = {-1.0f,  1.0f, 1.0f, -1.0f};
        const float Vx = vx_tab[v];
        const float Vy = vy_tab[v];
        const float ox = theta[b_*6+0]*Vx + theta[b_*6+1]*Vy + theta[b_*6+2];
        const float oy = theta[b_*6+3]*Vx + theta[b_*6+4]*Vy + theta[b_*6+5];
        float* vo = out + (size_t)B * C * OH * OW;
        vo[b_*8 + v*2 + 0] = (ox + 1.0f) * ((float)IW * 0.5f);
        vo[b_*8 + v*2 + 1] = (oy + 1.0f) * ((float)IH * 0.5f);
    }

    // ---- XCD-chunked bijective swizzle (512 contiguous ids = 2 batches/XCD) ----
    int id = (int)blockIdx.x;
    id = (id & 7) * (NB >> 3) + (id >> 3);

    const int wt = id & (NWT - 1);
    const int ht = (id >> 4) & (NHT - 1);
    const int b  = id >> 8;

    const int tx = tid & (TW - 1);
    const int ty = tid >> 4;
    const int w = wt * TW + tx;
    const int h = ht * TH + ty;

    const float t00 = theta[b*6+0], t01 = theta[b*6+1], t02 = theta[b*6+2];
    const float t10 = theta[b*6+3], t11 = theta[b*6+4], t12 = theta[b*6+5];

    const float sWn = 2.0f / (float)(OW - 1);
    const float sHn = 2.0f / (float)(OH - 1);

    // per-thread sample coordinates (align_corners linspace)
    const float wn = -1.0f + sWn * (float)w;
    const float hn = -1.0f + sHn * (float)h;
    const float ix = (t00 * wn + t01 * hn + t02 + 1.0f) * ((float)(IW - 1) * 0.5f);
    const float iy = (t10 * wn + t11 * hn + t12 + 1.0f) * ((float)(IH - 1) * 0.5f);

    const float x0f = floorf(ix);
    const float y0f = floorf(iy);
    const float wx1 = ix - x0f;
    const float wy1 = iy - y0f;
    const float wx0 = 1.0f - wx1;
    const float wy0 = 1.0f - wy1;

    const bool inx0 = (x0f >= 0.0f) && (x0f <= (float)(IW - 1));
    const bool inx1 = (x0f + 1.0f >= 0.0f) && (x0f + 1.0f <= (float)(IW - 1));
    const bool iny0 = (y0f >= 0.0f) && (y0f <= (float)(IH - 1));
    const bool iny1 = (y0f + 1.0f >= 0.0f) && (y0f + 1.0f <= (float)(IH - 1));

    const float w00 = (inx0 && iny0) ? wx0 * wy0 : 0.0f;
    const float w10 = (inx1 && iny0) ? wx1 * wy0 : 0.0f;
    const float w01 = (inx0 && iny1) ? wx0 * wy1 : 0.0f;
    const float w11 = (inx1 && iny1) ? wx1 * wy1 : 0.0f;

    // ---- tile bbox from the 4 tile corners (affine => extremes at corners) ----
    const float wnA = -1.0f + sWn * (float)(wt * TW);
    const float wnB = -1.0f + sWn * (float)(wt * TW + TW - 1);
    const float hnA = -1.0f + sHn * (float)(ht * TH);
    const float hnB = -1.0f + sHn * (float)(ht * TH + TH - 1);

    const float ixAA = (t00*wnA + t01*hnA + t02 + 1.0f) * 127.5f;
    const float ixAB = (t00*wnA + t01*hnB + t02 + 1.0f) * 127.5f;
    const float ixBA = (t00*wnB + t01*hnA + t02 + 1.0f) * 127.5f;
    const float ixBB = (t00*wnB + t01*hnB + t02 + 1.0f) * 127.5f;
    const float iyAA = (t10*wnA + t11*hnA + t12 + 1.0f) * 127.5f;
    const float iyAB = (t10*wnA + t11*hnB + t12 + 1.0f) * 127.5f;
    const float iyBA = (t10*wnB + t11*hnA + t12 + 1.0f) * 127.5f;
    const float iyBB = (t10*wnB + t11*hnB + t12 + 1.0f) * 127.5f;

    const float min_ix = fminf(fminf(ixAA, ixAB), fminf(ixBA, ixBB));
    const float max_ix = fmaxf(fmaxf(ixAA, ixAB), fmaxf(ixBA, ixBB));
    const float min_iy = fminf(fminf(iyAA, iyAB), fminf(iyBA, iyBB));
    const float max_iy = fmaxf(fmaxf(iyAA, iyAB), fmaxf(iyBA, iyBB));

    float* o = out + ((size_t)(b * C) << 16) + (size_t)(h * OW + w);

    // ---- whole-tile-OOB fast path: pure zero stores, no barriers ----
    if (max_ix < -1.0f || min_ix > 256.0f || max_iy < -1.0f || min_iy > 256.0f) {
        #pragma unroll 8
        for (int c = 0; c < C; ++c) {
            __builtin_nontemporal_store(0.0f, o);
            o += OH * OW;
        }
        return;
    }

    // ---- integer bbox (+-1 safety; weights are 0 wherever clamps bite) ----
    const int bx0 = min(max((int)floorf(min_ix) - 1, 0), IW - 1);
    const int bx1 = min(max((int)floorf(max_ix) + 2, 0), IW - 1);
    const int by0 = min(max((int)floorf(min_iy) - 1, 0), IH - 1);
    const int by1 = min(max((int)floorf(max_iy) + 2, 0), IH - 1);

    const int Wneed = bx1 - bx0 + 4;
    int lw = 32 - __builtin_clz((unsigned)(Wneed - 1));   // pow2ceil
    if (lw < 3) lw = 3;
    if (lw > 8) lw = 8;
    const int P    = 1 << lw;
    const int Pp   = P + 4;                  // pitch: rows shift 4 banks
    const int ax0p = min(bx0 & ~3, IW - P);  // 16B-aligned window start
    const int Hd   = by1 - by0 + 1;

    const int x0i = (int)x0f;
    const int y0i = (int)y0f;
    const float* plane = inp + ((size_t)(b * C) << 16);

    if (Hd * Pp > CAPU) {
        // ---- fallback (big bbox, ~7%): R0-style paired direct gathers ----
        const int  basex = min(max(x0i, 0), IW - 2);
        const bool sA = (x0i <= IW - 2);
        const bool sB = (x0i >= 0);
        const int  y0c = min(max(y0i,     0), IH - 1);
        const int  y1c = min(max(y0i + 1, 0), IH - 1);
        const int off0 = y0c * IW + basex;
        const int off1 = y1c * IW + basex;
        const float* pl = plane;
        for (int c = 0; c < C; ++c) {
            const f2 ra = *(const f2u*)(pl + off0);
            const f2 rb = *(const f2u*)(pl + off1);
            const float a00 = sA ? ra.x : ra.y;
            const float a10 = sB ? ra.y : ra.x;
            const float b00 = sA ? rb.x : rb.y;
            const float b11 = sB ? rb.y : rb.x;
            float v = w00 * a00;
            v = fmaf(w10, a10, v);
            v = fmaf(w01, b00, v);
            v = fmaf(w11, b11, v);
            __builtin_nontemporal_store(v, o);
            pl += IH * IW;
            o  += OH * OW;
        }
        return;
    }

    // ---- per-thread LDS sample offsets (channel-invariant) ----
    const int xin = x0i - ax0p;
    const int rin = y0i - by0;
    const int xc0 = min(max(xin, 0), P - 2);
    const bool selA = (xin <= P - 2);
    const bool selB = (xin >= 0);
    const int r0 = min(max(rin,     0), Hd - 1);
    const int r1 = min(max(rin + 1, 0), Hd - 1);
    const int ad0 = r0 * Pp + xc0;
    const int ad1 = r1 * Pp + xc0;

    // ---- staging map: LINEAR lane->window; UNCONDITIONAL 2 groups so the
    // per-wave outstanding-load count is uniform (counted vmcnt, no drain) ----
    const int S = Hd << lw;   // S = Hd*P <= Hd*Pp <= 1280 < 2048 (2 groups cover)
    int gsrc[2], ldst[2];
    #pragma unroll
    for (int g = 0; g < 2; ++g) {
        const int i4 = g * 1024 + (tid << 2);
        if (i4 < S) {
            const int r  = i4 >> lw;
            const int xb = i4 & (P - 1);
            gsrc[g] = (by0 + r) * IW + ax0p + xb;   // coalesced dwordx4
            ldst[g] = r * Pp + xb;
        } else {
            gsrc[g] = by0 * IW + ax0p;              // L1-hot dummy (valid addr)
            ldst[g] = CAPU + ((tid & 63) << 2);     // dump strip, conflict-free
        }
    }

    // 4 channel slots: [buf 0/1][ch 0/1 of pair]
    __shared__ float sb[2][2][CAPF];

    auto samp = [&](const float* Lb) -> float {
        const float p00 = Lb[ad0], p01 = Lb[ad0 + 1];
        const float p10 = Lb[ad1], p11 = Lb[ad1 + 1];
        const float a00 = selA ? p00 : p01;
        const float a10 = selB ? p01 : p00;
        const float c00 = selA ? p10 : p11;
        const float c11 = selB ? p11 : p10;
        float v = w00 * a00;
        v = fmaf(w10, a10, v);
        v = fmaf(w01, c00, v);
        v = fmaf(w11, c11, v);
        return v;
    };

    // ---- depth-2-PAIR pipeline: 1 barrier per 2 channels; loads issued a
    // full double-phase before their ds_write (4 channels of lookahead) ----
    const size_t PL = (size_t)(IH * IW);
    const float* pld = plane;
    f4 pfA00, pfA01, pfA10, pfA11;   // pair slot A: [ch][group]
    f4 pfB00, pfB01, pfB10, pfB11;   // pair slot B

    // prologue: pair0 -> slotA, pair1 -> slotB, write pair0 to buf0
    pfA00 = *(const f4*)(pld + gsrc[0]);
    pfA01 = *(const f4*)(pld + gsrc[1]);
    pfA10 = *(const f4*)(pld + PL + gsrc[0]);
    pfA11 = *(const f4*)(pld + PL + gsrc[1]);
    pld += 2 * PL;
    pfB00 = *(const f4*)(pld + gsrc[0]);
    pfB01 = *(const f4*)(pld + gsrc[1]);
    pfB10 = *(const f4*)(pld + PL + gsrc[0]);
    pfB11 = *(const f4*)(pld + PL + gsrc[1]);
    pld += 2 * PL;
    *(f4*)(&sb[0][0][0] + ldst[0]) = pfA00;   // counted vmcnt (slotB in flight)
    *(f4*)(&sb[0][0][0] + ldst[1]) = pfA01;
    *(f4*)(&sb[0][1][0] + ldst[0]) = pfA10;
    *(f4*)(&sb[0][1][0] + ldst[1]) = pfA11;
    BAR();

    #pragma unroll 1
    for (int k = 0; k < 15; ++k) {
        // even phase: sample pair 2k (buf0); write pair 2k+1 -> buf1; issue pair 2k+2 -> A
        pfA00 = *(const f4*)(pld + gsrc[0]);
        pfA01 = *(const f4*)(pld + gsrc[1]);
        pfA10 = *(const f4*)(pld + PL + gsrc[0]);
        pfA11 = *(const f4*)(pld + PL + gsrc[1]);
        pld += 2 * PL;
        *(f4*)(&sb[1][0][0] + ldst[0]) = pfB00;   // waits pair 2k+1 only
        *(f4*)(&sb[1][0][0] + ldst[1]) = pfB01;
        *(f4*)(&sb[1][1][0] + ldst[0]) = pfB10;
        *(f4*)(&sb[1][1][0] + ldst[1]) = pfB11;
        const float v0 = samp(&sb[0][0][0]);
        const float v1 = samp(&sb[0][1][0]);
        BAR();
        __builtin_nontemporal_store(v0, o);  o += OH * OW;
        __builtin_nontemporal_store(v1, o);  o += OH * OW;

        // odd phase: sample pair 2k+1 (buf1); write pair 2k+2 -> buf0; issue pair 2k+3 -> B
        pfB00 = *(const f4*)(pld + gsrc[0]);
        pfB01 = *(const f4*)(pld + gsrc[1]);
        pfB10 = *(const f4*)(pld + PL + gsrc[0]);
        pfB11 = *(const f4*)(pld + PL + gsrc[1]);
        pld += 2 * PL;
        *(f4*)(&sb[0][0][0] + ldst[0]) = pfA00;
        *(f4*)(&sb[0][0][0] + ldst[1]) = pfA01;
        *(f4*)(&sb[0][1][0] + ldst[0]) = pfA10;
        *(f4*)(&sb[0][1][0] + ldst[1]) = pfA11;
        const float v2 = samp(&sb[1][0][0]);
        const float v3 = samp(&sb[1][1][0]);
        BAR();
        __builtin_nontemporal_store(v2, o);  o += OH * OW;
        __builtin_nontemporal_store(v3, o);  o += OH * OW;
    }

    // epilogue: pair30 staged in buf0 (from loop k=14 odd); pair31 in slotB
    *(f4*)(&sb[1][0][0] + ldst[0]) = pfB00;
    *(f4*)(&sb[1][0][0] + ldst[1]) = pfB01;
    *(f4*)(&sb[1][1][0] + ldst[0]) = pfB10;
    *(f4*)(&sb[1][1][0] + ldst[1]) = pfB11;
    const float v0 = samp(&sb[0][0][0]);
    const float v1 = samp(&sb[0][1][0]);
    BAR();
    __builtin_nontemporal_store(v0, o);  o += OH * OW;
    __builtin_nontemporal_store(v1, o);  o += OH * OW;
    const float v2 = samp(&sb[1][0][0]);
    const float v3 = samp(&sb[1][1][0]);
    __builtin_nontemporal_store(v2, o);  o += OH * OW;
    __builtin_nontemporal_store(v3, o);
}

extern "C" void kernel_launch(void* const* d_in, const int* in_sizes, int n_in,
                              void* d_out, int out_size, void* d_ws, size_t ws_size,
                              hipStream_t stream) {
    const float* inp   = (const float*)d_in[0];
    const float* theta = (const float*)d_in[1];
    float* out = (float*)d_out;

    ast_fused<<<NB, 256, 0, stream>>>(inp, theta, out);
}

// Round 7
// 467.550 us; speedup vs baseline: 1.3026x; 1.1288x over previous
//
#include <hip/hip_runtime.h>

// Problem constants (fixed by setup_inputs in the reference)
#define B  16
#define C  64
#define IH 256
#define IW 256
#define OH 256
#define OW 256

// Tiling: each block = 32x8 output tile x 16 channels.
// NOTE (session evidence): this direct-gather form is TA-bound (~50 cyc per
// divergent wave-gather, shape-invariant: 32x2 vs 16x4 waves both ~170 µs).
// LDS-staging variants (coalesced dwordx4 stage + counted-vmcnt double
// buffering, depth-2 and depth-2-pair) all plateau at 218-302 µs — barrier/
// latency serialization exceeds the gather savings. XCD swizzle measured
// neutral-to-negative (no HBM over-fetch exists: FETCH ~50 MB). Keep this.
#define TW 32
#define TH 8
#define CC 16              // channels per block
#define NWT (OW / TW)      // 8
#define NHT (OH / TH)      // 32
#define NCC (C / CC)       // 4

// float2 vector with only 4-byte alignment guarantee: lets the compiler emit
// a wide load on targets with unaligned-access support, or split safely.
typedef float f2 __attribute__((ext_vector_type(2)));
typedef f2 __attribute__((aligned(4))) f2u;

__global__ __launch_bounds__(256) void ast_fused(const float* __restrict__ inp,
                                                 const float* __restrict__ theta,
                                                 float* __restrict__ out) {
    // ---- vertex output folded into block 0 (tiny: 128 floats) ----
    if (blockIdx.x == 0 && threadIdx.x < B * 4) {
        const int tid = threadIdx.x;
        const int b = tid >> 2;
        const int v = tid & 3;
        const float vx_tab[4] = {-1.0f, -1.0f, 1.0f, 1.0f};
        const float vy_tab[4] = {-1.0f,  1.0f, 1.0f, -1.0f};
        const float Vx = vx_tab[v];
        const float Vy = vy_tab[v];
        const float ox = theta[b*6+0]*Vx + theta[b*6+1]*Vy + theta[b*6+2];
        const float oy = theta[b*6+3]*Vx + theta[b*6+4]*Vy + theta[b*6+5];
        float* vo = out + (size_t)B * C * OH * OW;
        vo[b*8 + v*2 + 0] = (ox + 1.0f) * ((float)IW * 0.5f);
        vo[b*8 + v*2 + 1] = (oy + 1.0f) * ((float)IH * 0.5f);
    }

    // ---- decode block -> (b, channel-chunk, h-tile, w-tile) ----
    int id = blockIdx.x;
    const int wt = id & (NWT - 1); id >>= 3;   // 8 w-tiles
    const int ht = id & (NHT - 1); id >>= 5;   // 32 h-tiles
    const int cc = id & (NCC - 1); id >>= 2;   // 4 channel chunks
    const int b  = id;                         // 16 batches

    const int tx = threadIdx.x & (TW - 1);
    const int ty = threadIdx.x >> 5;
    const int w = wt * TW + tx;
    const int h = ht * TH + ty;

    // linspace(-1,1,N), align_corners
    const float wn = -1.0f + (2.0f / (float)(OW - 1)) * (float)w;
    const float hn = -1.0f + (2.0f / (float)(OH - 1)) * (float)h;

    const float t00 = theta[b*6+0], t01 = theta[b*6+1], t02 = theta[b*6+2];
    const float t10 = theta[b*6+3], t11 = theta[b*6+4], t12 = theta[b*6+5];

    const float gx = t00 * wn + t01 * hn + t02;
    const float gy = t10 * wn + t11 * hn + t12;

    const float ix = (gx + 1.0f) * ((float)(IW - 1) * 0.5f);
    const float iy = (gy + 1.0f) * ((float)(IH - 1) * 0.5f);

    const float x0f = floorf(ix);
    const float y0f = floorf(iy);

    const float wx1 = ix - x0f;
    const float wy1 = iy - y0f;
    const float wx0 = 1.0f - wx1;
    const float wy0 = 1.0f - wy1;

    const bool inx0 = (x0f >= 0.0f) && (x0f <= (float)(IW - 1));
    const bool inx1 = (x0f + 1.0f >= 0.0f) && (x0f + 1.0f <= (float)(IW - 1));
    const bool iny0 = (y0f >= 0.0f) && (y0f <= (float)(IH - 1));
    const bool iny1 = (y0f + 1.0f >= 0.0f) && (y0f + 1.0f <= (float)(IH - 1));

    const float w00 = (inx0 && iny0) ? wx0 * wy0 : 0.0f;
    const float w10 = (inx1 && iny0) ? wx1 * wy0 : 0.0f;
    const float w01 = (inx0 && iny1) ? wx0 * wy1 : 0.0f;
    const float w11 = (inx1 && iny1) ? wx1 * wy1 : 0.0f;

    // Paired-corner base x: pair covers (basex, basex+1); selects below pick
    // the right element for each corner (wrong element only where weight==0).
    const int  basex = (int)fminf(fmaxf(x0f, 0.0f), (float)(IW - 2));
    const bool selA  = (x0f <= (float)(IW - 2));   // corner x0 = pair.x
    const bool selB  = (x0f >= 0.0f);              // corner x1 = pair.y

    const int y0 = (int)fminf(fmaxf(y0f,        0.0f), (float)(IH - 1));
    const int y1 = (int)fminf(fmaxf(y0f + 1.0f, 0.0f), (float)(IH - 1));

    const int off0 = y0 * IW + basex;   // row y0: (x0c, x0c+1)
    const int off1 = y1 * IW + basex;   // row y1: (x0c, x0c+1)

    const bool any_in = (inx0 || inx1) && (iny0 || iny1);

    const int c0 = cc * CC;
    const float* __restrict__ p = inp + ((size_t)b * C + c0) * (IH * IW);
    float* __restrict__ o = out + (((size_t)b * C + c0) * OH + h) * OW + w;

    if (any_in) {
        #pragma unroll 16
        for (int c = 0; c < CC; ++c) {
            const f2 ra = *(const f2u*)(p + off0);
            const f2 rb = *(const f2u*)(p + off1);
            const float a00 = selA ? ra.x : ra.y;
            const float a10 = selB ? ra.y : ra.x;
            const float b00 = selA ? rb.x : rb.y;
            const float b11 = selB ? rb.y : rb.x;
            float v = w00 * a00;
            v = fmaf(w10, a10, v);
            v = fmaf(w01, b00, v);
            v = fmaf(w11, b11, v);
            __builtin_nontemporal_store(v, o);
            p += IH * IW;
            o += OH * OW;
        }
    } else {
        #pragma unroll 16
        for (int c = 0; c < CC; ++c) {
            __builtin_nontemporal_store(0.0f, o);
            o += OH * OW;
        }
    }
}

extern "C" void kernel_launch(void* const* d_in, const int* in_sizes, int n_in,
                              void* d_out, int out_size, void* d_ws, size_t ws_size,
                              hipStream_t stream) {
    const float* inp   = (const float*)d_in[0];
    const float* theta = (const float*)d_in[1];
    float* out = (float*)d_out;

    ast_fused<<<B * NCC * NHT * NWT, 256, 0, stream>>>(inp, theta, out);
}